// Round 5
// baseline (326.946 us; speedup 1.0000x reference)
//
#include <hip/hip_runtime.h>

typedef _Float16 f16;
typedef _Float16 f16x8 __attribute__((ext_vector_type(8)));
typedef float f32x4 __attribute__((ext_vector_type(4)));

#define BK 32

// Async global->LDS, 16B per lane: lane i's 16B lands at base + i*16.
__device__ __forceinline__ void g2l16(const void* g, void* l) {
    __builtin_amdgcn_global_load_lds(
        (const __attribute__((address_space(1))) void*)g,
        (__attribute__((address_space(3))) void*)l, 16, 0, 0);
}

__device__ __forceinline__ float soft1(float a, float thr, float w, float s) {
    return copysignf(fmaxf(a - thr, 0.0f), w) * s;
}

__device__ __forceinline__ float thr4(float a0, float a1, float a2, float a3) {
    float lo01 = fminf(a0, a1), hi01 = fmaxf(a0, a1);
    float lo23 = fminf(a2, a3), hi23 = fmaxf(a2, a3);
    return fminf(fmaxf(lo01, lo23), fminf(hi01, hi23));
}

// XCD swizzle: co-locate all nCol column-blocks of a row-block on one XCD.
// Assumes consecutive blockIdx round-robin across the 8 XCDs.
// bid = (r&7) | ((r>>3)*nCol + c) << 3   (requires nRow % 8 == 0)
template <int nCol>
__device__ __forceinline__ void decode_rc(int bid, int& r, int& c) {
    int hi = bid >> 3;
    r = ((hi / nCol) << 3) | (bid & 7);
    c = hi % nCol;
}

// prep: [0, nSpInB)   -> sparsify w_in (2:4 along R),   out winT  [R][D] f16
//       [nSpInB, ..)  -> sparsify w_out^T (2:4 along D), out woutT [D][R] f16
__global__ __launch_bounds__(256) void prep_kernel(
    const float* __restrict__ Wi, f16* __restrict__ winT, const float* __restrict__ sci,
    const float* __restrict__ Wo, f16* __restrict__ woutT, const float* __restrict__ sco,
    int D, int R, int nSpInB)
{
    int b = blockIdx.x;
    int tid = threadIdx.x;
    if (b < nSpInB) {
        int t = b * 256 + tid;              // t = rg*D + d (coalesced writes)
        int RG = R >> 2;
        if (t >= RG * D) return;
        int rg = t / D, d = t - rg * D;
        float s = *sci;
        float4 w = *reinterpret_cast<const float4*>(Wi + (size_t)d * R + rg * 4);
        float a0 = fabsf(w.x), a1 = fabsf(w.y), a2 = fabsf(w.z), a3 = fabsf(w.w);
        float thr = thr4(a0, a1, a2, a3);
        size_t base = (size_t)(rg * 4) * D + d;
        winT[base]                 = (f16)soft1(a0, thr, w.x, s);
        winT[base + D]             = (f16)soft1(a1, thr, w.y, s);
        winT[base + 2 * (size_t)D] = (f16)soft1(a2, thr, w.z, s);
        winT[base + 3 * (size_t)D] = (f16)soft1(a3, thr, w.w, s);
    } else {
        int t = (b - nSpInB) * 256 + tid;   // t = dg*R + r
        if (t >= (D >> 2) * R) return;
        int dg = t / R, r = t - dg * R;
        float s = *sco;
        size_t i0 = (size_t)(dg * 4) * R + r;
        float w0 = Wo[i0], w1 = Wo[i0 + R], w2 = Wo[i0 + 2 * (size_t)R], w3 = Wo[i0 + 3 * (size_t)R];
        float a0 = fabsf(w0), a1 = fabsf(w1), a2 = fabsf(w2), a3 = fabsf(w3);
        float thr = thr4(a0, a1, a2, a3);
        woutT[i0]                 = (f16)soft1(a0, thr, w0, s);
        woutT[i0 + R]             = (f16)soft1(a1, thr, w1, s);
        woutT[i0 + 2 * (size_t)R] = (f16)soft1(a2, thr, w2, s);
        woutT[i0 + 3 * (size_t)R] = (f16)soft1(a3, thr, w3, s);
    }
}

// GEMM1: h[M][N] f16 = f16(A[M][K] fp32) @ Bt[N][K]^T f16, fp32 accum.
// Tile 64x64, 2x2 waves (wave tile 32x32). A staged as fp32, cvt in-register.
__global__ __launch_bounds__(256) void gemm1_f32a(
    const float* __restrict__ A, const f16* __restrict__ Bt, f16* __restrict__ C,
    int M, int N, int K)
{
    __shared__ float Asf[64 * BK];   // [64][32] fp32, unpadded
    __shared__ f16   Bs[64 * BK];    // [64][32] f16,  unpadded

    const int tid  = threadIdx.x;
    const int lane = tid & 63;
    const int w    = tid >> 6;
    const int wm   = w & 1;
    const int wn   = w >> 1;
    const int l16  = lane & 15;
    const int quad = lane >> 4;

    int rb, cb;
    decode_rc<8>(blockIdx.x, rb, cb);   // N/64 = 8 column blocks
    const int bm = rb * 64;
    const int bn = cb * 64;

    // A staging (fp32): row = lane>>3 (8 rows/instr), col = (lane&7)*4 floats.
    // wave w covers rows [w*16, w*16+16) via 2 instrs.
    const int sArow = lane >> 3;
    const int sAcol = (lane & 7) * 4;
    const float* gA = A + (size_t)(bm + w * 16 + sArow) * K + sAcol;
    float* lA = &Asf[(w * 16) * BK];
    // B staging (f16): row = lane>>2 (16 rows/instr), col = (lane&3)*8 halves.
    const int sBrow = lane >> 2;
    const int sBcol = (lane & 3) * 8;
    const f16* gB = Bt + (size_t)(bn + w * 16 + sBrow) * K + sBcol;
    f16* lB = &Bs[(w * 16) * BK];

    f32x4 acc[2][2] = {};

    for (int k0 = 0; k0 < K; k0 += BK) {
        g2l16(gA + k0,                 lA);
        g2l16(gA + k0 + 8 * (size_t)K, lA + 8 * BK);
        g2l16(gB + k0,                 lB);
        __syncthreads();

        f16x8 af[2], bf[2];
#pragma unroll
        for (int m = 0; m < 2; ++m) {
            const float* p = &Asf[(wm * 32 + m * 16 + l16) * BK + quad * 8];
            float4 u = *reinterpret_cast<const float4*>(p);
            float4 v = *reinterpret_cast<const float4*>(p + 4);
            af[m] = f16x8{(f16)u.x, (f16)u.y, (f16)u.z, (f16)u.w,
                          (f16)v.x, (f16)v.y, (f16)v.z, (f16)v.w};
        }
#pragma unroll
        for (int n = 0; n < 2; ++n)
            bf[n] = *reinterpret_cast<const f16x8*>(&Bs[(wn * 32 + n * 16 + l16) * BK + quad * 8]);
#pragma unroll
        for (int m = 0; m < 2; ++m)
#pragma unroll
            for (int n = 0; n < 2; ++n)
                acc[m][n] = __builtin_amdgcn_mfma_f32_16x16x32_f16(af[m], bf[n], acc[m][n], 0, 0, 0);
        __syncthreads();
    }

    // epilogue: C/D layout row = quad*4 + r, col = lane&15
#pragma unroll
    for (int m = 0; m < 2; ++m) {
        int row_base = bm + wm * 32 + m * 16 + quad * 4;
#pragma unroll
        for (int n = 0; n < 2; ++n) {
            int col = bn + wn * 32 + n * 16 + l16;
#pragma unroll
            for (int r = 0; r < 4; ++r)
                C[(size_t)(row_base + r) * N + col] = (f16)acc[m][n][r];
        }
    }
}

// GEMM2: C[M][N] fp32 = A[M][K] f16 @ Bt[N][K]^T f16 + bias. Tile 64x128,
// 2x2 waves (wave tile 32x64). m97-style staging.
__global__ __launch_bounds__(256) void gemm2_bias(
    const f16* __restrict__ A, const f16* __restrict__ Bt, float* __restrict__ C,
    const float* __restrict__ bias, int M, int N, int K)
{
    __shared__ f16 As[64 * BK];
    __shared__ f16 Bs[128 * BK];

    const int tid  = threadIdx.x;
    const int lane = tid & 63;
    const int w    = tid >> 6;
    const int wm   = w & 1;
    const int wn   = w >> 1;
    const int l16  = lane & 15;
    const int quad = lane >> 4;

    int rb, cb;
    decode_rc<16>(blockIdx.x, rb, cb);   // N/128 = 16 column blocks
    const int bm = rb * 64;
    const int bn = cb * 128;

    const int srow = lane >> 2;
    const int scol = (lane & 3) * 8;
    const f16* gA = A  + (size_t)(bm + w * 16 + srow) * K + scol;
    const f16* gB = Bt + (size_t)(bn + w * 32 + srow) * K + scol;
    f16* lA = &As[(w * 16) * BK];
    f16* lB = &Bs[(w * 32) * BK];

    f32x4 acc[2][4] = {};

    for (int k0 = 0; k0 < K; k0 += BK) {
        g2l16(gA + k0,                  lA);
        g2l16(gB + k0,                  lB);
        g2l16(gB + k0 + 16 * (size_t)K, lB + 16 * BK);
        __syncthreads();

        f16x8 af[2], bf[4];
#pragma unroll
        for (int m = 0; m < 2; ++m)
            af[m] = *reinterpret_cast<const f16x8*>(&As[(wm * 32 + m * 16 + l16) * BK + quad * 8]);
#pragma unroll
        for (int n = 0; n < 4; ++n)
            bf[n] = *reinterpret_cast<const f16x8*>(&Bs[(wn * 64 + n * 16 + l16) * BK + quad * 8]);
#pragma unroll
        for (int m = 0; m < 2; ++m)
#pragma unroll
            for (int n = 0; n < 4; ++n)
                acc[m][n] = __builtin_amdgcn_mfma_f32_16x16x32_f16(af[m], bf[n], acc[m][n], 0, 0, 0);
        __syncthreads();
    }

#pragma unroll
    for (int m = 0; m < 2; ++m) {
        int row_base = bm + wm * 32 + m * 16 + quad * 4;
#pragma unroll
        for (int n = 0; n < 4; ++n) {
            int col = bn + wn * 64 + n * 16 + l16;
            float b = bias[col];
#pragma unroll
            for (int r = 0; r < 4; ++r)
                C[(size_t)(row_base + r) * N + col] = acc[m][n][r] + b;
        }
    }
}

extern "C" void kernel_launch(void* const* d_in, const int* in_sizes, int n_in,
                              void* d_out, int out_size, void* d_ws, size_t ws_size,
                              hipStream_t stream)
{
    const float* x      = (const float*)d_in[0];
    const float* w_in   = (const float*)d_in[1];
    const float* w_out  = (const float*)d_in[2];
    const float* bias   = (const float*)d_in[3];
    const float* sc_in  = (const float*)d_in[4];
    const float* sc_out = (const float*)d_in[5];

    const int D = in_sizes[3];            // 2048
    const int R = in_sizes[1] / D;        // 512
    const int M = in_sizes[0] / D;        // 8192 (B*S)

    f16* winT  = (f16*)d_ws;                      // [R][D]
    f16* woutT = winT + (size_t)R * D;            // [D][R]
    f16* h     = woutT + (size_t)D * R;           // [M][R]
    float* out = (float*)d_out;

    const int nSpInB  = ((R / 4) * D + 255) / 256;
    const int nSpOutB = ((D / 4) * R + 255) / 256;
    prep_kernel<<<nSpInB + nSpOutB, 256, 0, stream>>>(
        w_in, winT, sc_in, w_out, woutT, sc_out, D, R, nSpInB);

    // GEMM1: grid (M/64)*(R/64) = 128*8 = 1024 blocks, XCD-swizzled
    gemm1_f32a<<<(M / 64) * (R / 64), 256, 0, stream>>>(x, winT, h, M, R, D);
    // GEMM2: grid (M/64)*(D/128) = 128*16 = 2048 blocks, XCD-swizzled
    gemm2_bias<<<(M / 64) * (D / 128), 256, 0, stream>>>(h, woutT, out, bias, M, D, R);
}

// Round 6
// 207.191 us; speedup vs baseline: 1.5780x; 1.5780x over previous
//
#include <hip/hip_runtime.h>

typedef _Float16 f16;
typedef _Float16 f16x8 __attribute__((ext_vector_type(8)));
typedef float f32x4 __attribute__((ext_vector_type(4)));

#define BK 32

// Async global->LDS, 16B per lane: lane i's 16B lands at base + i*16.
__device__ __forceinline__ void g2l16(const void* g, void* l) {
    __builtin_amdgcn_global_load_lds(
        (const __attribute__((address_space(1))) void*)g,
        (__attribute__((address_space(3))) void*)l, 16, 0, 0);
}

__device__ __forceinline__ float soft1(float a, float thr, float w, float s) {
    return copysignf(fmaxf(a - thr, 0.0f), w) * s;
}

__device__ __forceinline__ float thr4(float a0, float a1, float a2, float a3) {
    float lo01 = fminf(a0, a1), hi01 = fmaxf(a0, a1);
    float lo23 = fminf(a2, a3), hi23 = fmaxf(a2, a3);
    return fminf(fmaxf(lo01, lo23), fminf(hi01, hi23));
}

// XCD swizzle: co-locate all nCol column-blocks of a row-block on one XCD.
// bid = (r&7) | ((r>>3)*nCol + c) << 3   (requires nRow % 8 == 0)
template <int nCol>
__device__ __forceinline__ void decode_rc(int bid, int& r, int& c) {
    int hi = bid >> 3;
    r = ((hi / nCol) << 3) | (bid & 7);
    c = hi % nCol;
}

// prep: [0, nSpInB)   -> sparsify w_in (2:4 along R),    out winT  [R][D] f16
//       [nSpInB, ..)  -> sparsify w_out^T (2:4 along D), out woutT [D][R] f16
__global__ __launch_bounds__(256) void prep_kernel(
    const float* __restrict__ Wi, f16* __restrict__ winT, const float* __restrict__ sci,
    const float* __restrict__ Wo, f16* __restrict__ woutT, const float* __restrict__ sco,
    int D, int R, int nSpInB)
{
    int b = blockIdx.x;
    int tid = threadIdx.x;
    if (b < nSpInB) {
        int t = b * 256 + tid;              // t = rg*D + d (coalesced writes)
        int RG = R >> 2;
        if (t >= RG * D) return;
        int rg = t / D, d = t - rg * D;
        float s = *sci;
        float4 w = *reinterpret_cast<const float4*>(Wi + (size_t)d * R + rg * 4);
        float a0 = fabsf(w.x), a1 = fabsf(w.y), a2 = fabsf(w.z), a3 = fabsf(w.w);
        float thr = thr4(a0, a1, a2, a3);
        size_t base = (size_t)(rg * 4) * D + d;
        winT[base]                 = (f16)soft1(a0, thr, w.x, s);
        winT[base + D]             = (f16)soft1(a1, thr, w.y, s);
        winT[base + 2 * (size_t)D] = (f16)soft1(a2, thr, w.z, s);
        winT[base + 3 * (size_t)D] = (f16)soft1(a3, thr, w.w, s);
    } else {
        int t = (b - nSpInB) * 256 + tid;   // t = dg*R + r
        if (t >= (D >> 2) * R) return;
        int dg = t / R, r = t - dg * R;
        float s = *sco;
        size_t i0 = (size_t)(dg * 4) * R + r;
        float w0 = Wo[i0], w1 = Wo[i0 + R], w2 = Wo[i0 + 2 * (size_t)R], w3 = Wo[i0 + 3 * (size_t)R];
        float a0 = fabsf(w0), a1 = fabsf(w1), a2 = fabsf(w2), a3 = fabsf(w3);
        float thr = thr4(a0, a1, a2, a3);
        woutT[i0]                 = (f16)soft1(a0, thr, w0, s);
        woutT[i0 + R]             = (f16)soft1(a1, thr, w1, s);
        woutT[i0 + 2 * (size_t)R] = (f16)soft1(a2, thr, w2, s);
        woutT[i0 + 3 * (size_t)R] = (f16)soft1(a3, thr, w3, s);
    }
}

// GEMM1: h[M][N] f16 = f16(A[M][K] fp32) @ Bt[N][K]^T f16, fp32 accum.
// Tile 64x64, 2x2 waves. A staged fp32 with XOR-swizzled layout:
// logical float4-chunk c of row r lives at LDS chunk c ^ (r&7), implemented
// by permuting the per-lane *source* address (LDS dest order is HW-fixed).
// Fragment reads then hit 2 lanes/bank (free) instead of 16 (the round-5 bug).
__global__ __launch_bounds__(256) void gemm1_f32a(
    const float* __restrict__ A, const f16* __restrict__ Bt, f16* __restrict__ C,
    int M, int N, int K)
{
    __shared__ float Asf[64 * BK];   // [64][32] fp32, XOR-swizzled chunks
    __shared__ f16   Bs[64 * BK];    // [64][32] f16, unpadded (bank-balanced)

    const int tid  = threadIdx.x;
    const int lane = tid & 63;
    const int w    = tid >> 6;
    const int wm   = w & 1;
    const int wn   = w >> 1;
    const int l16  = lane & 15;
    const int quad = lane >> 4;

    int rb, cb;
    decode_rc<8>(blockIdx.x, rb, cb);   // N/64 = 8 column blocks
    const int bm = rb * 64;
    const int bn = cb * 64;

    // A staging: one instr = 8 rows x 32 floats. row-in-group = lane>>3 (== r&7),
    // source chunk = (lane&7) ^ (lane>>3)  -> lands at LDS chunk lane&7.
    const int sArow   = lane >> 3;
    const int sAchunk = (lane & 7) ^ sArow;
    const float* gA = A + (size_t)(bm + w * 16 + sArow) * K + sAchunk * 4;
    float* lA = &Asf[(w * 16) * BK];
    // B staging (f16): row = lane>>2 (16 rows/instr), col = (lane&3)*8 halves.
    const int sBrow = lane >> 2;
    const int sBcol = (lane & 3) * 8;
    const f16* gB = Bt + (size_t)(bn + w * 16 + sBrow) * K + sBcol;
    f16* lB = &Bs[(w * 16) * BK];

    f32x4 acc[2][2] = {};

    for (int k0 = 0; k0 < K; k0 += BK) {
        g2l16(gA + k0,                 lA);
        g2l16(gA + k0 + 8 * (size_t)K, lA + 8 * BK);
        g2l16(gB + k0,                 lB);
        __syncthreads();

        f16x8 af[2], bf[2];
#pragma unroll
        for (int m = 0; m < 2; ++m) {
            int rm = wm * 32 + m * 16 + l16;
            int s  = l16 & 7;           // == rm & 7
            const float* pu = &Asf[rm * BK + (((2 * quad)     ^ s) * 4)];
            const float* pv = &Asf[rm * BK + (((2 * quad + 1) ^ s) * 4)];
            float4 u = *reinterpret_cast<const float4*>(pu);
            float4 v = *reinterpret_cast<const float4*>(pv);
            af[m] = f16x8{(f16)u.x, (f16)u.y, (f16)u.z, (f16)u.w,
                          (f16)v.x, (f16)v.y, (f16)v.z, (f16)v.w};
        }
#pragma unroll
        for (int n = 0; n < 2; ++n)
            bf[n] = *reinterpret_cast<const f16x8*>(&Bs[(wn * 32 + n * 16 + l16) * BK + quad * 8]);
#pragma unroll
        for (int m = 0; m < 2; ++m)
#pragma unroll
            for (int n = 0; n < 2; ++n)
                acc[m][n] = __builtin_amdgcn_mfma_f32_16x16x32_f16(af[m], bf[n], acc[m][n], 0, 0, 0);
        __syncthreads();
    }

    // epilogue: C/D layout row = quad*4 + r, col = lane&15
#pragma unroll
    for (int m = 0; m < 2; ++m) {
        int row_base = bm + wm * 32 + m * 16 + quad * 4;
#pragma unroll
        for (int n = 0; n < 2; ++n) {
            int col = bn + wn * 32 + n * 16 + l16;
#pragma unroll
            for (int r = 0; r < 4; ++r)
                C[(size_t)(row_base + r) * N + col] = (f16)acc[m][n][r];
        }
    }
}

// GEMM2: C[M][N] fp32 = A[M][K] f16 @ Bt[N][K]^T f16 + bias. Tile 64x128,
// 2x2 waves (wave tile 32x64). m97-style staging, XCD-swizzled.
__global__ __launch_bounds__(256) void gemm2_bias(
    const f16* __restrict__ A, const f16* __restrict__ Bt, float* __restrict__ C,
    const float* __restrict__ bias, int M, int N, int K)
{
    __shared__ f16 As[64 * BK];
    __shared__ f16 Bs[128 * BK];

    const int tid  = threadIdx.x;
    const int lane = tid & 63;
    const int w    = tid >> 6;
    const int wm   = w & 1;
    const int wn   = w >> 1;
    const int l16  = lane & 15;
    const int quad = lane >> 4;

    int rb, cb;
    decode_rc<16>(blockIdx.x, rb, cb);   // N/128 = 16 column blocks
    const int bm = rb * 64;
    const int bn = cb * 128;

    const int srow = lane >> 2;
    const int scol = (lane & 3) * 8;
    const f16* gA = A  + (size_t)(bm + w * 16 + srow) * K + scol;
    const f16* gB = Bt + (size_t)(bn + w * 32 + srow) * K + scol;
    f16* lA = &As[(w * 16) * BK];
    f16* lB = &Bs[(w * 32) * BK];

    f32x4 acc[2][4] = {};

    for (int k0 = 0; k0 < K; k0 += BK) {
        g2l16(gA + k0,                  lA);
        g2l16(gB + k0,                  lB);
        g2l16(gB + k0 + 16 * (size_t)K, lB + 16 * BK);
        __syncthreads();

        f16x8 af[2], bf[4];
#pragma unroll
        for (int m = 0; m < 2; ++m)
            af[m] = *reinterpret_cast<const f16x8*>(&As[(wm * 32 + m * 16 + l16) * BK + quad * 8]);
#pragma unroll
        for (int n = 0; n < 4; ++n)
            bf[n] = *reinterpret_cast<const f16x8*>(&Bs[(wn * 64 + n * 16 + l16) * BK + quad * 8]);
#pragma unroll
        for (int m = 0; m < 2; ++m)
#pragma unroll
            for (int n = 0; n < 4; ++n)
                acc[m][n] = __builtin_amdgcn_mfma_f32_16x16x32_f16(af[m], bf[n], acc[m][n], 0, 0, 0);
        __syncthreads();
    }

#pragma unroll
    for (int m = 0; m < 2; ++m) {
        int row_base = bm + wm * 32 + m * 16 + quad * 4;
#pragma unroll
        for (int n = 0; n < 4; ++n) {
            int col = bn + wn * 64 + n * 16 + l16;
            float b = bias[col];
#pragma unroll
            for (int r = 0; r < 4; ++r)
                C[(size_t)(row_base + r) * N + col] = acc[m][n][r] + b;
        }
    }
}

extern "C" void kernel_launch(void* const* d_in, const int* in_sizes, int n_in,
                              void* d_out, int out_size, void* d_ws, size_t ws_size,
                              hipStream_t stream)
{
    const float* x      = (const float*)d_in[0];
    const float* w_in   = (const float*)d_in[1];
    const float* w_out  = (const float*)d_in[2];
    const float* bias   = (const float*)d_in[3];
    const float* sc_in  = (const float*)d_in[4];
    const float* sc_out = (const float*)d_in[5];

    const int D = in_sizes[3];            // 2048
    const int R = in_sizes[1] / D;        // 512
    const int M = in_sizes[0] / D;        // 8192 (B*S)

    f16* winT  = (f16*)d_ws;                      // [R][D]
    f16* woutT = winT + (size_t)R * D;            // [D][R]
    f16* h     = woutT + (size_t)D * R;           // [M][R]
    float* out = (float*)d_out;

    const int nSpInB  = ((R / 4) * D + 255) / 256;
    const int nSpOutB = ((D / 4) * R + 255) / 256;
    prep_kernel<<<nSpInB + nSpOutB, 256, 0, stream>>>(
        w_in, winT, sc_in, w_out, woutT, sc_out, D, R, nSpInB);

    // GEMM1: grid (M/64)*(R/64) = 128*8 = 1024 blocks, XCD-swizzled
    gemm1_f32a<<<(M / 64) * (R / 64), 256, 0, stream>>>(x, winT, h, M, R, D);
    // GEMM2: grid (M/64)*(D/128) = 128*16 = 2048 blocks, XCD-swizzled
    gemm2_bias<<<(M / 64) * (D / 128), 256, 0, stream>>>(h, woutT, out, bias, M, D, R);
}